// Round 1
// baseline (2968.204 us; speedup 1.0000x reference)
//
#include <hip/hip_runtime.h>
#include <hip/hip_bf16.h>

// 2-layer GCN (PyG GCNConv semantics) on MI355X.
// N=100000 nodes, E=1.6M edges, IN=128, HID=64, OUT=64.
//
// Algebra: y = (x@W) * dinv[row];  agg[d] = y[d] + sum_{e:(s->d)} y[s];
//          out[d] = agg[d]*dinv[d] + b   (self-loop folded into agg init).

#define IN_DIM 128
#define HID 64

__global__ void init_deg_kernel(int* __restrict__ deg, int N) {
  int i = blockIdx.x * blockDim.x + threadIdx.x;
  if (i < N) deg[i] = 1;  // self loop
}

__global__ void count_deg_kernel(const int* __restrict__ dst, int* __restrict__ deg, int E) {
  int i = blockIdx.x * blockDim.x + threadIdx.x;
  if (i < E) atomicAdd(&deg[dst[i]], 1);
}

__global__ void dinv_kernel(const int* __restrict__ deg, float* __restrict__ dinv, int N) {
  int i = blockIdx.x * blockDim.x + threadIdx.x;
  if (i < N) dinv[i] = rsqrtf((float)deg[i]);
}

// y1 = (x @ W1) * dinv[row]; agg1 = y1 (self-loop init).
// One wave per row: 64 lanes = 64 output columns. W1 (128x64, 32KB) in LDS.
__global__ __launch_bounds__(256) void gemm1_kernel(
    const float* __restrict__ x, const float* __restrict__ W1,
    const float* __restrict__ dinv, float* __restrict__ y1,
    float* __restrict__ agg1, int N) {
  __shared__ float Ws[IN_DIM * HID];
  for (int i = threadIdx.x; i < IN_DIM * HID / 4; i += 256)
    ((float4*)Ws)[i] = ((const float4*)W1)[i];
  __syncthreads();

  int wave = threadIdx.x >> 6;
  int lane = threadIdx.x & 63;
  int r = blockIdx.x * 4 + wave;
  bool valid = r < N;
  int rr = valid ? r : 0;

  const float* xr = x + (size_t)rr * IN_DIM;
  float acc = 0.f;
#pragma unroll
  for (int k = 0; k < IN_DIM; k += 4) {
    float4 xv = *(const float4*)(xr + k);  // wave-uniform addr -> broadcast
    acc = fmaf(xv.x, Ws[(k + 0) * HID + lane], acc);
    acc = fmaf(xv.y, Ws[(k + 1) * HID + lane], acc);
    acc = fmaf(xv.z, Ws[(k + 2) * HID + lane], acc);
    acc = fmaf(xv.w, Ws[(k + 3) * HID + lane], acc);
  }
  if (valid) {
    float v = acc * dinv[r];
    y1[(size_t)r * HID + lane] = v;
    agg1[(size_t)r * HID + lane] = v;
  }
}

// agg[dst] += y[src], 16 lanes per edge, float4 gather + 4 HW float atomics.
__global__ __launch_bounds__(256) void scatter_kernel(
    const int* __restrict__ src, const int* __restrict__ dst,
    const float* __restrict__ y, float* __restrict__ agg, int E) {
  int t = blockIdx.x * blockDim.x + threadIdx.x;
  int e = t >> 4;
  if (e >= E) return;
  int q = (t & 15) << 2;
  int s = src[e], d = dst[e];
  const float4 v = *(const float4*)(y + (size_t)s * HID + q);
  float* ap = agg + (size_t)d * HID + q;
  unsafeAtomicAdd(ap + 0, v.x);
  unsafeAtomicAdd(ap + 1, v.y);
  unsafeAtomicAdd(ap + 2, v.z);
  unsafeAtomicAdd(ap + 3, v.w);
}

// h = relu(agg1*dinv + b1); y2 = (h @ W2) * dinv; out(=agg2 init) = y2.
__global__ __launch_bounds__(256) void layer2_kernel(
    const float* __restrict__ agg1, const float* __restrict__ W2,
    const float* __restrict__ b1, const float* __restrict__ dinv,
    float* __restrict__ y2, float* __restrict__ out, int N) {
  __shared__ float Ws[HID * HID];   // 16KB
  __shared__ float hs[4][HID];
  for (int i = threadIdx.x; i < HID * HID / 4; i += 256)
    ((float4*)Ws)[i] = ((const float4*)W2)[i];

  int wave = threadIdx.x >> 6;
  int lane = threadIdx.x & 63;
  int r = blockIdx.x * 4 + wave;
  bool valid = r < N;
  int rr = valid ? r : 0;

  float di = dinv[rr];
  float a = agg1[(size_t)rr * HID + lane];
  float h = fmaxf(fmaf(a, di, b1[lane]), 0.f);
  hs[wave][lane] = h;
  __syncthreads();  // covers Ws load + hs visibility

  float acc = 0.f;
#pragma unroll
  for (int k = 0; k < HID; k += 4) {
    float4 hv = *(const float4*)&hs[wave][k];
    acc = fmaf(hv.x, Ws[(k + 0) * HID + lane], acc);
    acc = fmaf(hv.y, Ws[(k + 1) * HID + lane], acc);
    acc = fmaf(hv.z, Ws[(k + 2) * HID + lane], acc);
    acc = fmaf(hv.w, Ws[(k + 3) * HID + lane], acc);
  }
  if (valid) {
    float v = acc * di;
    y2[(size_t)r * HID + lane] = v;
    out[(size_t)r * HID + lane] = v;
  }
}

__global__ void finalize_kernel(float* __restrict__ out, const float* __restrict__ dinv,
                                const float* __restrict__ b2, int total) {
  int i = blockIdx.x * blockDim.x + threadIdx.x;
  if (i < total) {
    int r = i >> 6, c = i & 63;
    out[i] = fmaf(out[i], dinv[r], b2[c]);
  }
}

extern "C" void kernel_launch(void* const* d_in, const int* in_sizes, int n_in,
                              void* d_out, int out_size, void* d_ws, size_t ws_size,
                              hipStream_t stream) {
  const float* x  = (const float*)d_in[0];
  const int* edges = (const int*)d_in[1];
  const float* W1 = (const float*)d_in[2];
  const float* b1 = (const float*)d_in[3];
  const float* W2 = (const float*)d_in[4];
  const float* b2 = (const float*)d_in[5];
  float* out = (float*)d_out;

  const int N = in_sizes[0] / IN_DIM;   // 100000
  const int E = in_sizes[1] / 2;        // 1600000
  const int* src = edges;
  const int* dst = edges + E;

  char* wsb = (char*)d_ws;
  int*   deg  = (int*)(wsb);                       // N ints
  float* dinv = (float*)(wsb + 524288);            // N floats
  float* y1   = (float*)(wsb + 1048576);           // N*64 floats (25.6MB)
  float* agg1 = (float*)(wsb + 1048576 + (size_t)N * HID * 4);
  float* y2   = y1;  // y1 dead after scatter1; reuse

  const int blk = 256;
  int gN  = (N + blk - 1) / blk;
  int gE  = (E + blk - 1) / blk;
  int gR  = (N + 3) / 4;                 // 4 rows (waves) per block
  int gS  = (E * 16 + blk - 1) / blk;    // 16 lanes per edge
  int gF  = (N * HID + blk - 1) / blk;

  init_deg_kernel<<<gN, blk, 0, stream>>>(deg, N);
  count_deg_kernel<<<gE, blk, 0, stream>>>(dst, deg, E);
  dinv_kernel<<<gN, blk, 0, stream>>>(deg, dinv, N);

  gemm1_kernel<<<gR, blk, 0, stream>>>(x, W1, dinv, y1, agg1, N);
  scatter_kernel<<<gS, blk, 0, stream>>>(src, dst, y1, agg1, E);

  layer2_kernel<<<gR, blk, 0, stream>>>(agg1, W2, b1, dinv, y2, out, N);
  scatter_kernel<<<gS, blk, 0, stream>>>(src, dst, y2, out, E);

  finalize_kernel<<<gF, blk, 0, stream>>>(out, dinv, b2, N * HID);
}

// Round 2
// 587.832 us; speedup vs baseline: 5.0494x; 5.0494x over previous
//
#include <hip/hip_runtime.h>
#include <hip/hip_bf16.h>

// 2-layer GCN (PyG GCNConv) on MI355X. N=100000, E=1.6M, IN=128, HID=OUT=64.
//
// Algebra: y = (x@W) * dinv[row]; agg[d] = y[d] + sum_{e:(s->d)} y[s];
//          out[d] = agg[d]*dinv[d] + b  (self-loop folded into agg init).
// Aggregation via CSR gather (built once, reused by both layers) -> no float atomics.

#define IN_DIM 128
#define HID 64
#define SCAN_B 256

__global__ void count_kernel(const int* __restrict__ dst, int* __restrict__ cnt, int E) {
  int i = blockIdx.x * blockDim.x + threadIdx.x;
  if (i < E) atomicAdd(&cnt[dst[i]], 1);
}

// Block-level inclusive scan -> exclusive rowptr (partial) + block sums; also dinv.
__global__ __launch_bounds__(SCAN_B) void scan1_kernel(
    const int* __restrict__ cnt, int* __restrict__ rowptr, int* __restrict__ bsum,
    float* __restrict__ dinv, int N) {
  __shared__ int s[SCAN_B];
  int i = blockIdx.x * SCAN_B + threadIdx.x;
  int v = (i < N) ? cnt[i] : 0;
  if (i < N) dinv[i] = rsqrtf((float)(v + 1));  // +1 self loop
  s[threadIdx.x] = v;
  __syncthreads();
  for (int off = 1; off < SCAN_B; off <<= 1) {
    int t = (threadIdx.x >= off) ? s[threadIdx.x - off] : 0;
    __syncthreads();
    s[threadIdx.x] += t;
    __syncthreads();
  }
  if (i < N) rowptr[i] = s[threadIdx.x] - v;          // exclusive within block
  if (threadIdx.x == SCAN_B - 1) bsum[blockIdx.x] = s[SCAN_B - 1];
}

// Scan block sums (NB <= 512) in one block -> exclusive.
__global__ __launch_bounds__(512) void scan2_kernel(int* __restrict__ bsum, int NB) {
  __shared__ int s[512];
  int v = (threadIdx.x < NB) ? bsum[threadIdx.x] : 0;
  s[threadIdx.x] = v;
  __syncthreads();
  for (int off = 1; off < 512; off <<= 1) {
    int t = (threadIdx.x >= off) ? s[threadIdx.x - off] : 0;
    __syncthreads();
    s[threadIdx.x] += t;
    __syncthreads();
  }
  if (threadIdx.x < NB) bsum[threadIdx.x] = s[threadIdx.x] - v;
}

__global__ void scan3_kernel(int* __restrict__ rowptr, const int* __restrict__ bsum,
                             int* __restrict__ cursor, int N, int E) {
  int i = blockIdx.x * blockDim.x + threadIdx.x;
  if (i < N) {
    int p = rowptr[i] + bsum[i / SCAN_B];
    rowptr[i] = p;
    cursor[i] = p;
  }
  if (i == 0) rowptr[N] = E;
}

__global__ void fill_kernel(const int* __restrict__ src, const int* __restrict__ dst,
                            int* __restrict__ cursor, int* __restrict__ csr_src, int E) {
  int e = blockIdx.x * blockDim.x + threadIdx.x;
  if (e < E) {
    int pos = atomicAdd(&cursor[dst[e]], 1);
    csr_src[pos] = src[e];
  }
}

// y1 = (x @ W1) * dinv[row]. One wave per row; 64 lanes = 64 out cols; W1 in LDS.
__global__ __launch_bounds__(256) void gemm1_kernel(
    const float* __restrict__ x, const float* __restrict__ W1,
    const float* __restrict__ dinv, float* __restrict__ y1, int N) {
  __shared__ float Ws[IN_DIM * HID];
  for (int i = threadIdx.x; i < IN_DIM * HID / 4; i += 256)
    ((float4*)Ws)[i] = ((const float4*)W1)[i];
  __syncthreads();

  int wave = threadIdx.x >> 6, lane = threadIdx.x & 63;
  int r = blockIdx.x * 4 + wave;
  if (r >= N) return;
  const float* xr = x + (size_t)r * IN_DIM;
  float acc = 0.f;
#pragma unroll
  for (int k = 0; k < IN_DIM; k += 4) {
    float4 xv = *(const float4*)(xr + k);
    acc = fmaf(xv.x, Ws[(k + 0) * HID + lane], acc);
    acc = fmaf(xv.y, Ws[(k + 1) * HID + lane], acc);
    acc = fmaf(xv.z, Ws[(k + 2) * HID + lane], acc);
    acc = fmaf(xv.w, Ws[(k + 3) * HID + lane], acc);
  }
  y1[(size_t)r * HID + lane] = acc * dinv[r];
}

// h = relu((y1[r] + sum_in y1[s]) * dinv[r] + b1). One wave per node.
__global__ __launch_bounds__(256) void agg1_kernel(
    const float* __restrict__ y1, const int* __restrict__ rowptr,
    const int* __restrict__ csr_src, const float* __restrict__ dinv,
    const float* __restrict__ b1, float* __restrict__ h, int N) {
  int wave = threadIdx.x >> 6, lane = threadIdx.x & 63;
  int r = blockIdx.x * 4 + wave;
  if (r >= N) return;
  float acc = y1[(size_t)r * HID + lane];
  int j = rowptr[r], end = rowptr[r + 1];
  for (; j + 1 < end; j += 2) {
    int s0 = csr_src[j], s1 = csr_src[j + 1];
    float v0 = y1[(size_t)s0 * HID + lane];
    float v1 = y1[(size_t)s1 * HID + lane];
    acc += v0 + v1;
  }
  if (j < end) acc += y1[(size_t)csr_src[j] * HID + lane];
  h[(size_t)r * HID + lane] = fmaxf(fmaf(acc, dinv[r], b1[lane]), 0.f);
}

// y2 = (h @ W2) * dinv[row]. W2 (64x64) in LDS.
__global__ __launch_bounds__(256) void gemm2_kernel(
    const float* __restrict__ h, const float* __restrict__ W2,
    const float* __restrict__ dinv, float* __restrict__ y2, int N) {
  __shared__ float Ws[HID * HID];
  for (int i = threadIdx.x; i < HID * HID / 4; i += 256)
    ((float4*)Ws)[i] = ((const float4*)W2)[i];
  __syncthreads();

  int wave = threadIdx.x >> 6, lane = threadIdx.x & 63;
  int r = blockIdx.x * 4 + wave;
  if (r >= N) return;
  const float* hr = h + (size_t)r * HID;
  float acc = 0.f;
#pragma unroll
  for (int k = 0; k < HID; k += 4) {
    float4 hv = *(const float4*)(hr + k);
    acc = fmaf(hv.x, Ws[(k + 0) * HID + lane], acc);
    acc = fmaf(hv.y, Ws[(k + 1) * HID + lane], acc);
    acc = fmaf(hv.z, Ws[(k + 2) * HID + lane], acc);
    acc = fmaf(hv.w, Ws[(k + 3) * HID + lane], acc);
  }
  y2[(size_t)r * HID + lane] = acc * dinv[r];
}

// out = (y2[r] + sum_in y2[s]) * dinv[r] + b2.
__global__ __launch_bounds__(256) void agg2_kernel(
    const float* __restrict__ y2, const int* __restrict__ rowptr,
    const int* __restrict__ csr_src, const float* __restrict__ dinv,
    const float* __restrict__ b2, float* __restrict__ out, int N) {
  int wave = threadIdx.x >> 6, lane = threadIdx.x & 63;
  int r = blockIdx.x * 4 + wave;
  if (r >= N) return;
  float acc = y2[(size_t)r * HID + lane];
  int j = rowptr[r], end = rowptr[r + 1];
  for (; j + 1 < end; j += 2) {
    int s0 = csr_src[j], s1 = csr_src[j + 1];
    float v0 = y2[(size_t)s0 * HID + lane];
    float v1 = y2[(size_t)s1 * HID + lane];
    acc += v0 + v1;
  }
  if (j < end) acc += y2[(size_t)csr_src[j] * HID + lane];
  out[(size_t)r * HID + lane] = fmaf(acc, dinv[r], b2[lane]);
}

extern "C" void kernel_launch(void* const* d_in, const int* in_sizes, int n_in,
                              void* d_out, int out_size, void* d_ws, size_t ws_size,
                              hipStream_t stream) {
  const float* x   = (const float*)d_in[0];
  const int* edges = (const int*)d_in[1];
  const float* W1  = (const float*)d_in[2];
  const float* b1  = (const float*)d_in[3];
  const float* W2  = (const float*)d_in[4];
  const float* b2  = (const float*)d_in[5];
  float* out = (float*)d_out;

  const int N = in_sizes[0] / IN_DIM;   // 100000
  const int E = in_sizes[1] / 2;        // 1600000
  const int* src = edges;
  const int* dst = edges + E;

  char* wsb = (char*)d_ws;
  int*   cnt     = (int*)(wsb + 0);               // N
  float* dinv    = (float*)(wsb + (1u << 19));    // N
  int*   rowptr  = (int*)(wsb + (2u << 19));      // N+1
  int*   cursor  = (int*)(wsb + (3u << 19));      // N
  int*   bsum    = (int*)(wsb + (4u << 19));      // <=512
  int*   csr_src = (int*)(wsb + (5u << 19));      // E (6.4MB)
  float* y1      = (float*)(wsb + (16u << 20));   // N*64 (25.6MB)
  float* h       = (float*)(wsb + (48u << 20));   // N*64 (25.6MB)
  float* y2      = y1;                            // y1 dead after agg1

  const int blk = 256;
  int gE = (E + blk - 1) / blk;
  int gN = (N + blk - 1) / blk;
  int NB = (N + SCAN_B - 1) / SCAN_B;             // 391 <= 512
  int gR = (N + 3) / 4;                           // 4 waves (rows) per block

  hipMemsetAsync(cnt, 0, (size_t)N * 4, stream);
  count_kernel<<<gE, blk, 0, stream>>>(dst, cnt, E);
  scan1_kernel<<<NB, SCAN_B, 0, stream>>>(cnt, rowptr, bsum, dinv, N);
  scan2_kernel<<<1, 512, 0, stream>>>(bsum, NB);
  scan3_kernel<<<gN, blk, 0, stream>>>(rowptr, bsum, cursor, N, E);
  fill_kernel<<<gE, blk, 0, stream>>>(src, dst, cursor, csr_src, E);

  gemm1_kernel<<<gR, blk, 0, stream>>>(x, W1, dinv, y1, N);
  agg1_kernel<<<gR, blk, 0, stream>>>(y1, rowptr, csr_src, dinv, b1, h, N);
  gemm2_kernel<<<gR, blk, 0, stream>>>(h, W2, dinv, y2, N);
  agg2_kernel<<<gR, blk, 0, stream>>>(y2, rowptr, csr_src, dinv, b2, out, N);
}

// Round 3
// 415.129 us; speedup vs baseline: 7.1501x; 1.4160x over previous
//
#include <hip/hip_runtime.h>
#include <hip/hip_bf16.h>

// 2-layer GCN (PyG GCNConv) on MI355X. N=100000, E=1.6M, IN=128, HID=OUT=64.
//
// Algebra: y = (x@W) * dinv[row]; agg[d] = y[d] + sum_{e:(s->d)} y[s];
//          out[d] = agg[d]*dinv[d] + b  (self-loop folded into agg init).
// CSR gather aggregation (no float atomics); gemm2 fused into agg1 epilogue.

#define IN_DIM 128
#define HID 64
#define SCAN_B 256
#define XS_STRIDE 68  // 64 + 4: float4-aligned, breaks pow2 bank pattern

__global__ void count_kernel(const int* __restrict__ dst, int* __restrict__ cnt, int E) {
  int i = blockIdx.x * blockDim.x + threadIdx.x;
  if (i < E) atomicAdd(&cnt[dst[i]], 1);
}

__global__ __launch_bounds__(SCAN_B) void scan1_kernel(
    const int* __restrict__ cnt, int* __restrict__ rowptr, int* __restrict__ bsum,
    float* __restrict__ dinv, int N) {
  __shared__ int s[SCAN_B];
  int i = blockIdx.x * SCAN_B + threadIdx.x;
  int v = (i < N) ? cnt[i] : 0;
  if (i < N) dinv[i] = rsqrtf((float)(v + 1));  // +1 self loop
  s[threadIdx.x] = v;
  __syncthreads();
  for (int off = 1; off < SCAN_B; off <<= 1) {
    int t = (threadIdx.x >= off) ? s[threadIdx.x - off] : 0;
    __syncthreads();
    s[threadIdx.x] += t;
    __syncthreads();
  }
  if (i < N) rowptr[i] = s[threadIdx.x] - v;
  if (threadIdx.x == SCAN_B - 1) bsum[blockIdx.x] = s[SCAN_B - 1];
}

__global__ __launch_bounds__(512) void scan2_kernel(int* __restrict__ bsum, int NB) {
  __shared__ int s[512];
  int v = (threadIdx.x < NB) ? bsum[threadIdx.x] : 0;
  s[threadIdx.x] = v;
  __syncthreads();
  for (int off = 1; off < 512; off <<= 1) {
    int t = (threadIdx.x >= off) ? s[threadIdx.x - off] : 0;
    __syncthreads();
    s[threadIdx.x] += t;
    __syncthreads();
  }
  if (threadIdx.x < NB) bsum[threadIdx.x] = s[threadIdx.x] - v;
}

__global__ void scan3_kernel(int* __restrict__ rowptr, const int* __restrict__ bsum,
                             int* __restrict__ cursor, int N, int E) {
  int i = blockIdx.x * blockDim.x + threadIdx.x;
  if (i < N) {
    int p = rowptr[i] + bsum[i / SCAN_B];
    rowptr[i] = p;
    cursor[i] = p;
  }
  if (i == 0) rowptr[N] = E;
}

__global__ void fill_kernel(const int* __restrict__ src, const int* __restrict__ dst,
                            int* __restrict__ cursor, int* __restrict__ csr_src, int E) {
  int e = blockIdx.x * blockDim.x + threadIdx.x;
  if (e < E) {
    int pos = atomicAdd(&cursor[dst[e]], 1);
    csr_src[pos] = src[e];
  }
}

// y1 = (x @ W1) * dinv[row]. Register-tiled: 64x64 tile/block, 4x4 acc/thread.
__global__ __launch_bounds__(256) void gemm1_kernel(
    const float* __restrict__ x, const float* __restrict__ W1,
    const float* __restrict__ dinv, float* __restrict__ y1, int N) {
  __shared__ float Xs[IN_DIM][XS_STRIDE];  // transposed: Xs[k][row]
  __shared__ float Ws[IN_DIM * HID];       // Ws[k*64+c]

  for (int i = threadIdx.x; i < IN_DIM * HID / 4; i += 256)
    ((float4*)Ws)[i] = ((const float4*)W1)[i];

  int r0 = blockIdx.x * 64;
  {  // stage x transposed: 4 threads per row, 8 float4 each
    int row = threadIdx.x >> 2;
    int kc = (threadIdx.x & 3) * 32;
    int gr = r0 + row;
    const float* xp = x + (size_t)(gr < N ? gr : N - 1) * IN_DIM + kc;
#pragma unroll
    for (int i = 0; i < 8; ++i) {
      float4 v = *(const float4*)(xp + i * 4);
      int k = kc + i * 4;
      Xs[k + 0][row] = v.x;
      Xs[k + 1][row] = v.y;
      Xs[k + 2][row] = v.z;
      Xs[k + 3][row] = v.w;
    }
  }
  __syncthreads();

  int tr = (threadIdx.x & 15) * 4;  // row group
  int tc = (threadIdx.x >> 4) * 4;  // col group
  float acc[4][4];
#pragma unroll
  for (int i = 0; i < 4; ++i)
#pragma unroll
    for (int j = 0; j < 4; ++j) acc[i][j] = 0.f;

#pragma unroll 8
  for (int k = 0; k < IN_DIM; ++k) {
    float4 a = *(const float4*)&Xs[k][tr];
    float4 b = *(const float4*)&Ws[k * HID + tc];
    acc[0][0] = fmaf(a.x, b.x, acc[0][0]); acc[0][1] = fmaf(a.x, b.y, acc[0][1]);
    acc[0][2] = fmaf(a.x, b.z, acc[0][2]); acc[0][3] = fmaf(a.x, b.w, acc[0][3]);
    acc[1][0] = fmaf(a.y, b.x, acc[1][0]); acc[1][1] = fmaf(a.y, b.y, acc[1][1]);
    acc[1][2] = fmaf(a.y, b.z, acc[1][2]); acc[1][3] = fmaf(a.y, b.w, acc[1][3]);
    acc[2][0] = fmaf(a.z, b.x, acc[2][0]); acc[2][1] = fmaf(a.z, b.y, acc[2][1]);
    acc[2][2] = fmaf(a.z, b.z, acc[2][2]); acc[2][3] = fmaf(a.z, b.w, acc[2][3]);
    acc[3][0] = fmaf(a.w, b.x, acc[3][0]); acc[3][1] = fmaf(a.w, b.y, acc[3][1]);
    acc[3][2] = fmaf(a.w, b.z, acc[3][2]); acc[3][3] = fmaf(a.w, b.w, acc[3][3]);
  }

#pragma unroll
  for (int i = 0; i < 4; ++i) {
    int r = r0 + tr + i;
    if (r < N) {
      float di = dinv[r];
      float4 v = make_float4(acc[i][0] * di, acc[i][1] * di, acc[i][2] * di, acc[i][3] * di);
      *(float4*)(y1 + (size_t)r * HID + tc) = v;
    }
  }
}

// h[r] = relu((y1[r] + sum_in y1[s]) * dinv[r] + b1); y2[r] = (h[r] @ W2) * dinv[r].
__global__ __launch_bounds__(256) void agg1_gemm2_kernel(
    const float* __restrict__ y1, const int* __restrict__ rowptr,
    const int* __restrict__ csr_src, const float* __restrict__ dinv,
    const float* __restrict__ b1, const float* __restrict__ W2,
    float* __restrict__ y2, int N) {
  __shared__ float Ws[HID * HID];  // 16KB
  __shared__ float hs[4][HID];
  for (int i = threadIdx.x; i < HID * HID / 4; i += 256)
    ((float4*)Ws)[i] = ((const float4*)W2)[i];

  int wave = threadIdx.x >> 6, lane = threadIdx.x & 63;
  int r = blockIdx.x * 4 + wave;
  bool valid = r < N;
  int rr = valid ? r : N - 1;

  int jb = rowptr[rr], je = rowptr[rr + 1];
  int cnt = je - jb;
  int m = cnt < 64 ? cnt : 64;
  int idx = (lane < cnt) ? csr_src[jb + lane] : 0;

  float a0 = y1[(size_t)rr * HID + lane];  // self loop
  float a1 = 0.f, a2 = 0.f, a3 = 0.f;
  int i = 0;
  for (; i + 3 < m; i += 4) {
    int s0 = __shfl(idx, i), s1 = __shfl(idx, i + 1);
    int s2 = __shfl(idx, i + 2), s3 = __shfl(idx, i + 3);
    a0 += y1[(size_t)s0 * HID + lane];
    a1 += y1[(size_t)s1 * HID + lane];
    a2 += y1[(size_t)s2 * HID + lane];
    a3 += y1[(size_t)s3 * HID + lane];
  }
  for (; i < m; ++i) {
    int s = __shfl(idx, i);
    a0 += y1[(size_t)s * HID + lane];
  }
  for (int j = jb + 64; j < je; ++j)  // degree > 64 tail (rare)
    a0 += y1[(size_t)csr_src[j] * HID + lane];
  float acc = (a0 + a1) + (a2 + a3);

  float di = dinv[rr];
  hs[wave][lane] = fmaxf(fmaf(acc, di, b1[lane]), 0.f);
  __syncthreads();  // Ws staged + hs visible

  float c0 = 0.f, c1 = 0.f, c2 = 0.f, c3 = 0.f;
#pragma unroll
  for (int k = 0; k < HID; k += 4) {
    float4 hv = *(const float4*)&hs[wave][k];
    c0 = fmaf(hv.x, Ws[(k + 0) * HID + lane], c0);
    c1 = fmaf(hv.y, Ws[(k + 1) * HID + lane], c1);
    c2 = fmaf(hv.z, Ws[(k + 2) * HID + lane], c2);
    c3 = fmaf(hv.w, Ws[(k + 3) * HID + lane], c3);
  }
  if (valid) y2[(size_t)r * HID + lane] = ((c0 + c1) + (c2 + c3)) * di;
}

// out[r] = (y2[r] + sum_in y2[s]) * dinv[r] + b2.
__global__ __launch_bounds__(256) void agg2_kernel(
    const float* __restrict__ y2, const int* __restrict__ rowptr,
    const int* __restrict__ csr_src, const float* __restrict__ dinv,
    const float* __restrict__ b2, float* __restrict__ out, int N) {
  int wave = threadIdx.x >> 6, lane = threadIdx.x & 63;
  int r = blockIdx.x * 4 + wave;
  if (r >= N) return;

  int jb = rowptr[r], je = rowptr[r + 1];
  int cnt = je - jb;
  int m = cnt < 64 ? cnt : 64;
  int idx = (lane < cnt) ? csr_src[jb + lane] : 0;

  float a0 = y2[(size_t)r * HID + lane];
  float a1 = 0.f, a2 = 0.f, a3 = 0.f;
  int i = 0;
  for (; i + 3 < m; i += 4) {
    int s0 = __shfl(idx, i), s1 = __shfl(idx, i + 1);
    int s2 = __shfl(idx, i + 2), s3 = __shfl(idx, i + 3);
    a0 += y2[(size_t)s0 * HID + lane];
    a1 += y2[(size_t)s1 * HID + lane];
    a2 += y2[(size_t)s2 * HID + lane];
    a3 += y2[(size_t)s3 * HID + lane];
  }
  for (; i < m; ++i) {
    int s = __shfl(idx, i);
    a0 += y2[(size_t)s * HID + lane];
  }
  for (int j = jb + 64; j < je; ++j)
    a0 += y2[(size_t)csr_src[j] * HID + lane];
  float acc = (a0 + a1) + (a2 + a3);

  out[(size_t)r * HID + lane] = fmaf(acc, dinv[r], b2[lane]);
}

extern "C" void kernel_launch(void* const* d_in, const int* in_sizes, int n_in,
                              void* d_out, int out_size, void* d_ws, size_t ws_size,
                              hipStream_t stream) {
  const float* x   = (const float*)d_in[0];
  const int* edges = (const int*)d_in[1];
  const float* W1  = (const float*)d_in[2];
  const float* b1  = (const float*)d_in[3];
  const float* W2  = (const float*)d_in[4];
  const float* b2  = (const float*)d_in[5];
  float* out = (float*)d_out;

  const int N = in_sizes[0] / IN_DIM;   // 100000
  const int E = in_sizes[1] / 2;        // 1600000
  const int* src = edges;
  const int* dst = edges + E;

  char* wsb = (char*)d_ws;
  int*   cnt     = (int*)(wsb + 0);               // N
  float* dinv    = (float*)(wsb + (1u << 19));    // N
  int*   rowptr  = (int*)(wsb + (2u << 19));      // N+1
  int*   cursor  = (int*)(wsb + (3u << 19));      // N
  int*   bsum    = (int*)(wsb + (4u << 19));      // <=512
  int*   csr_src = (int*)(wsb + (5u << 19));      // E (6.4MB)
  float* y1      = (float*)(wsb + (16u << 20));   // N*64 (25.6MB)
  float* y2      = (float*)(wsb + (48u << 20));   // N*64 (25.6MB)

  const int blk = 256;
  int gE = (E + blk - 1) / blk;
  int gN = (N + blk - 1) / blk;
  int NB = (N + SCAN_B - 1) / SCAN_B;             // 391 <= 512
  int gG = (N + 63) / 64;                         // gemm1: 64 rows/block
  int gR = (N + 3) / 4;                           // 4 waves (rows) per block

  hipMemsetAsync(cnt, 0, (size_t)N * 4, stream);
  count_kernel<<<gE, blk, 0, stream>>>(dst, cnt, E);
  scan1_kernel<<<NB, SCAN_B, 0, stream>>>(cnt, rowptr, bsum, dinv, N);
  scan2_kernel<<<1, 512, 0, stream>>>(bsum, NB);
  scan3_kernel<<<gN, blk, 0, stream>>>(rowptr, bsum, cursor, N, E);
  fill_kernel<<<gE, blk, 0, stream>>>(src, dst, cursor, csr_src, E);

  gemm1_kernel<<<gG, blk, 0, stream>>>(x, W1, dinv, y1, N);
  agg1_gemm2_kernel<<<gR, blk, 0, stream>>>(y1, rowptr, csr_src, dinv, b1, W2, y2, N);
  agg2_kernel<<<gR, blk, 0, stream>>>(y2, rowptr, csr_src, dinv, b2, out, N);
}